// Round 5
// baseline (1434.585 us; speedup 1.0000x reference)
//
#include <hip/hip_runtime.h>
#include <stdint.h>

#define DEVI __device__ __forceinline__
typedef unsigned long long ull;

typedef __bf16 bf16x8 __attribute__((ext_vector_type(8)));
typedef float floatx4 __attribute__((ext_vector_type(4)));

// ---------- helpers ----------
DEVI uint16_t f2bf(float f) {
  union { float f; uint32_t u; } c; c.f = f;
  uint32_t u = c.u;
  return (uint16_t)((u + 0x7fffu + ((u >> 16) & 1u)) >> 16);  // RNE
}
DEVI float bf2f(uint16_t h) {
  union { uint32_t u; float f; } c; c.u = ((uint32_t)h) << 16;
  return c.f;
}
DEVI void load_lds_16(const void* g, void* l) {
  __builtin_amdgcn_global_load_lds(
      (const __attribute__((address_space(1))) void*)g,
      (__attribute__((address_space(3))) void*)l, 16, 0, 0);
}
DEVI float sigm(float x) { return 1.f / (1.f + __expf(-x)); }
DEVI float tanh_s(float x) {
  float xc = fminf(fmaxf(x, -15.f), 15.f);
  float e = __expf(2.f * xc);
  return (e - 1.f) / (e + 1.f);
}

// ---------- workspace layout (bytes) ----------
// pre [256][64][2048] bf16; h slab for step t>=2 aliases pre[t-2] (first 16KB
// of each bg's 64KB row-group — consumed & GEMM-flushed before slab write).
// Slab layout: [16 rows][512 cols] bf16 = 16KB per (t, bg).
static constexpr size_t OFF_EMB    = 0;                        // [50000][256] bf16
static constexpr size_t OFF_WXT    = 25600000;                 // [2048][4096] bf16
static constexpr size_t OFF_WHT    = OFF_WXT + 16777216;       // [2048][512] bf16
static constexpr size_t OFF_BIAS   = OFF_WHT + 2097152;        // [2048] f32
static constexpr size_t OFF_PRE    = OFF_BIAS + 8192;          // [256][64][2048] bf16
static constexpr size_t OFF_HF     = OFF_PRE + 67108864 + 4096;
static constexpr size_t OFF_CF     = OFF_HF + 131072;
static constexpr size_t OFF_CNT    = OFF_CF + 131072;          // cnt[128] @+0, flags[64] @+2048 (memset 0)
static constexpr size_t OFF_SLAB01 = OFF_CNT + 4096;           // 2 x 65536 slabs for t=0,1

// ---------- 1. embedding -> bf16, row 0 zeroed ----------
__global__ __launch_bounds__(256) void k_emb_cvt(const float* __restrict__ emb,
                                                 uint16_t* __restrict__ dst) {
  size_t tid = (size_t)blockIdx.x * 256 + threadIdx.x;
  size_t e = tid * 8;
  int v = (int)(e >> 8);
  const float4* s = (const float4*)(emb + e);
  float4 f0 = s[0], f1 = s[1];
  if (v == 0) { f0 = make_float4(0.f, 0.f, 0.f, 0.f); f1 = f0; }
  uint32_t w0 = f2bf(f0.x) | ((uint32_t)f2bf(f0.y) << 16);
  uint32_t w1 = f2bf(f0.z) | ((uint32_t)f2bf(f0.w) << 16);
  uint32_t w2 = f2bf(f1.x) | ((uint32_t)f2bf(f1.y) << 16);
  uint32_t w3 = f2bf(f1.z) | ((uint32_t)f2bf(f1.w) << 16);
  *(uint4*)(dst + e) = make_uint4(w0, w1, w2, w3);
}

// ---------- 2. weight transpose+convert: W_g[K][512] -> dst[n=h*4+g][K] bf16 ----------
__global__ __launch_bounds__(256) void k_wt(const float* __restrict__ w0, const float* __restrict__ w1,
                                            const float* __restrict__ w2, const float* __restrict__ w3,
                                            int K, uint16_t* __restrict__ dst) {
  __shared__ float tile[64 * 64];
  int k0 = blockIdx.x * 64;
  int n0 = blockIdx.y * 64;
  int h0 = blockIdx.y * 16;
  int g = threadIdx.x >> 6, di = threadIdx.x & 63;
  const float* w = (g == 0) ? w0 : (g == 1) ? w1 : (g == 2) ? w2 : w3;
  const float4* src = (const float4*)(w + (size_t)(k0 + di) * 512 + h0);
  float4 a = src[0], b = src[1], c = src[2], d = src[3];
  float vals[16] = {a.x, a.y, a.z, a.w, b.x, b.y, b.z, b.w,
                    c.x, c.y, c.z, c.w, d.x, d.y, d.z, d.w};
#pragma unroll
  for (int dh = 0; dh < 16; ++dh) tile[(dh * 4 + g) * 64 + di] = vals[dh];
  __syncthreads();
  int nl = threadIdx.x >> 2, ch = threadIdx.x & 3;
  uint32_t wb[8];
#pragma unroll
  for (int j = 0; j < 8; ++j) {
    float lo = tile[nl * 64 + ch * 16 + j * 2];
    float hi = tile[nl * 64 + ch * 16 + j * 2 + 1];
    wb[j] = f2bf(lo) | ((uint32_t)f2bf(hi) << 16);
  }
  uint4* dp = (uint4*)(dst + (size_t)(n0 + nl) * K + k0 + ch * 16);
  dp[0] = make_uint4(wb[0], wb[1], wb[2], wb[3]);
  dp[1] = make_uint4(wb[4], wb[5], wb[6], wb[7]);
}

// ---------- 3. bias pack ----------
__global__ __launch_bounds__(256) void k_bias(const float* __restrict__ b0, const float* __restrict__ b1,
                                              const float* __restrict__ b2, const float* __restrict__ b3,
                                              float* __restrict__ dst) {
  int n = blockIdx.x * 256 + threadIdx.x;
  int h = n >> 2, g = n & 3;
  const float* b = (g == 0) ? b0 : (g == 1) ? b1 : (g == 2) ? b2 : b3;
  dst[n] = b[h];
}

// ---------- 4. merged GEMM + persistent recurrence ----------
// blocks 0..63: recurrence (resident immediately). blocks 64..2111: GEMM
// tiles, mtile-major ascending t; release-add on cnt[mtile] after vmcnt drain.
__global__ __launch_bounds__(256) void k_main(const uint16_t* embbf, const int* x,
                                              const uint16_t* wxt, uint16_t* pre,
                                              char* preb, char* slab01,
                                              const uint16_t* wht, const float* biasp,
                                              int* cnt, float* hfin, float* cfin) {
  __shared__ __align__(16) char smem[42240];
  const int tid = threadIdx.x;
  const int wv = tid >> 6, ln = tid & 63;
  const int q = ln >> 4, l16 = ln & 15;

  if (blockIdx.x >= 64) {
    // ================= GEMM part (unchanged) =================
    const int bid = blockIdx.x - 64;
    const int mtile = bid >> 4;
    const int M0 = mtile * 128, N0 = (bid & 15) * 128;
    uint16_t* As = (uint16_t*)smem;
    uint16_t* Bs = As + 128 * 64;
    const int wm = wv >> 1, wn = wv & 1;
    const int srow = ln >> 3, schunk = ln & 7;

    const int* xrow[4];
    const uint16_t* bbase[4];
    uint16_t* ldsA[4];
    uint16_t* ldsB[4];
#pragma unroll
    for (int j = 0; j < 4; ++j) {
      int r = j * 32 + wv * 8 + srow;
      int m = M0 + r;
      int t = m >> 6, b = m & 63;
      xrow[j] = x + b * 4096 + t;
      bbase[j] = wxt + (size_t)(N0 + r) * 4096 + schunk * 8;
      ldsA[j] = As + (j * 32 + wv * 8) * 64;
      ldsB[j] = Bs + (j * 32 + wv * 8) * 64;
    }
    int aoff[4], boff[4];
#pragma unroll
    for (int mt = 0; mt < 4; ++mt) aoff[mt] = (wm * 64 + mt * 16 + l16) * 64 + q * 8;
#pragma unroll
    for (int nt = 0; nt < 4; ++nt) boff[nt] = (wn * 64 + nt * 16 + l16) * 64 + q * 8;

    floatx4 acc[4][4] = {};
    for (int p = 0; p < 16; ++p) {
      const uint16_t* abase[4];
#pragma unroll
      for (int j = 0; j < 4; ++j) {
        int idx = xrow[j][p << 8];
        abase[j] = embbf + (size_t)idx * 256 + schunk * 8;
      }
#pragma unroll 1
      for (int ki = 0; ki < 4; ++ki) {
        __syncthreads();
#pragma unroll
        for (int j = 0; j < 4; ++j) load_lds_16(abase[j] + ki * 64, ldsA[j]);
#pragma unroll
        for (int j = 0; j < 4; ++j) load_lds_16(bbase[j] + p * 256 + ki * 64, ldsB[j]);
        __syncthreads();
#pragma unroll
        for (int kk = 0; kk < 2; ++kk) {
          bf16x8 a[4];
#pragma unroll
          for (int mt = 0; mt < 4; ++mt) a[mt] = *(const bf16x8*)(As + aoff[mt] + kk * 32);
#pragma unroll
          for (int nt = 0; nt < 4; ++nt) {
            bf16x8 bv = *(const bf16x8*)(Bs + boff[nt] + kk * 32);
#pragma unroll
            for (int mt = 0; mt < 4; ++mt)
              acc[mt][nt] = __builtin_amdgcn_mfma_f32_16x16x32_bf16(a[mt], bv, acc[mt][nt], 0, 0, 0);
          }
        }
      }
    }
#pragma unroll
    for (int mt = 0; mt < 4; ++mt) {
      int mg = M0 + wm * 64 + mt * 16 + q * 4;
#pragma unroll
      for (int nt = 0; nt < 4; ++nt) {
        int ng = N0 + wn * 64 + nt * 16 + l16;
#pragma unroll
        for (int r = 0; r < 4; ++r)
          pre[(size_t)(mg + r) * 2048 + ng] = f2bf(acc[mt][nt][r]);
      }
    }
    __syncthreads();  // drains vmcnt(0): all C stores acked
    if (tid == 0)
      __hip_atomic_fetch_add(&cnt[mtile], 1, __ATOMIC_RELEASE, __HIP_MEMORY_SCOPE_AGENT);
    return;
  }

  // ================= recurrence part =================
  // Ahs stride 528 elems (132 dw === 4 mod 32): MFMA A-reads & staging <=4-way
  uint16_t* Ahs[2];
  Ahs[0] = (uint16_t*)smem;                 // [16 x 528] each
  Ahs[1] = Ahs[0] + 16 * 528;
  float* gates = (float*)(smem + 33792);    // [16 x 132]
  int* flags = cnt + 512;                   // 64 ints, memset 0

  const int bg = blockIdx.x >> 4, cg = blockIdx.x & 15;
  const int N0 = cg * 128;

  // B fragments resident: wave wv owns n-cols N0 + wv*32 .. +32
  bf16x8 Bfrag[16][2];
#pragma unroll
  for (int kc = 0; kc < 16; ++kc)
#pragma unroll
    for (int nt = 0; nt < 2; ++nt) {
      int n = N0 + wv * 32 + nt * 16 + l16;
      Bfrag[kc][nt] = *(const bf16x8*)(wht + (size_t)n * 512 + kc * 32 + q * 8);
    }
  float breg[2];
#pragma unroll
  for (int nt = 0; nt < 2; ++nt) breg[nt] = biasp[N0 + wv * 32 + nt * 16 + l16];

  const int srow_ = tid & 15;               // payload row 0..15
  const int sseg_ = tid >> 4;               // 64B segment 0..15
  const int erow = ln >> 2;
  const int es = ln & 3;
  float creg[2] = {0.f, 0.f};

  // zero Ahs[0] (t=0 state h=0)
  for (int i = tid; i < 4224; i += 256) ((uint32_t*)Ahs[0])[i] = 0;

  int done_m = -1;
  auto wait_mtile = [&](int m) {
    if (m > done_m) {
      while (__hip_atomic_load(&cnt[m], __ATOMIC_RELAXED, __HIP_MEMORY_SCOPE_AGENT) < 16)
        __builtin_amdgcn_s_sleep(8);
      __builtin_amdgcn_fence(__ATOMIC_ACQUIRE, "agent");
      done_m = m;
    }
  };

  // register prefetch of pre strip for t=0 (gated on GEMM mtile 0)
  uint16_t pr[8];
  wait_mtile(0);
#pragma unroll
  for (int nt = 0; nt < 2; ++nt)
#pragma unroll
    for (int r = 0; r < 4; ++r)
      pr[nt * 4 + r] = pre[(size_t)(bg * 16 + q * 4 + r) * 2048 + N0 + wv * 32 + nt * 16 + l16];

  for (int t = 0; t < 256; ++t) {
    if (t > 0) {
      // low-traffic flag poll: one 4B flag per thread, then bulk payload (1 RT)
      const int fidx = bg * 16 + (tid & 15);
      while (__hip_atomic_load(&flags[fidx], __ATOMIC_RELAXED, __HIP_MEMORY_SCOPE_AGENT) < t)
        __builtin_amdgcn_s_sleep(1);
      __syncthreads();  // all 16 producers confirmed by the group
      const char* sb = ((t - 1) < 2 ? slab01 + (size_t)(t - 1) * 65536
                                    : preb + (size_t)(t - 3) * 262144) + (size_t)bg * ((t - 1) < 2 ? 16384 : 65536);
      const ull* pp = (const ull*)(sb + srow_ * 1024 + sseg_ * 64);
      ull v[8];
#pragma unroll
      for (int j = 0; j < 8; ++j)
        v[j] = __hip_atomic_load(pp + j, __ATOMIC_RELAXED, __HIP_MEMORY_SCOPE_AGENT);
      uint16_t* dr = Ahs[t & 1] + srow_ * 528 + sseg_ * 32;
#pragma unroll
      for (int j = 0; j < 8; ++j) *(ull*)(dr + j * 4) = v[j];
    }
    __syncthreads();

    // MFMA [16 x 512] x [512 x 32] per wave, 2 chains of 8
    const uint16_t* Ab = Ahs[t & 1];
    floatx4 a0[2] = {}, a1[2] = {};
#pragma unroll
    for (int kc = 0; kc < 8; ++kc) {
      bf16x8 a = *(const bf16x8*)(Ab + l16 * 528 + kc * 32 + q * 8);
#pragma unroll
      for (int nt = 0; nt < 2; ++nt)
        a0[nt] = __builtin_amdgcn_mfma_f32_16x16x32_bf16(a, Bfrag[kc][nt], a0[nt], 0, 0, 0);
    }
#pragma unroll
    for (int kc = 8; kc < 16; ++kc) {
      bf16x8 a = *(const bf16x8*)(Ab + l16 * 528 + kc * 32 + q * 8);
#pragma unroll
      for (int nt = 0; nt < 2; ++nt)
        a1[nt] = __builtin_amdgcn_mfma_f32_16x16x32_bf16(a, Bfrag[kc][nt], a1[nt], 0, 0, 0);
    }

    // gates = acc + bias + pre (registers, wave-local columns)
#pragma unroll
    for (int nt = 0; nt < 2; ++nt) {
      int n_l = wv * 32 + nt * 16 + l16;
      floatx4 s = a0[nt] + a1[nt];
#pragma unroll
      for (int r = 0; r < 4; ++r) {
        int row = q * 4 + r;
        gates[row * 132 + n_l] = s[r] + breg[nt] + bf2f(pr[nt * 4 + r]);
      }
    }
    // wave-local LDS exchange: compiler inserts lgkmcnt wait, no barrier

    // epilogue: 2 h-units per lane; 4B agent store into slab(t)
    {
      float4 v0 = *(const float4*)(gates + erow * 132 + wv * 32 + es * 8);
      float4 v1 = *(const float4*)(gates + erow * 132 + wv * 32 + es * 8 + 4);
      float f0 = sigm(v0.x), i0 = sigm(v0.y), g0 = tanh_s(v0.z), o0 = sigm(v0.w);
      float f1 = sigm(v1.x), i1 = sigm(v1.y), g1 = tanh_s(v1.z), o1 = sigm(v1.w);
      float c0 = f0 * creg[0] + i0 * g0; creg[0] = c0;
      float c1 = f1 * creg[1] + i1 * g1; creg[1] = c1;
      float h0 = o0 * tanh_s(c0), h1 = o1 * tanh_s(c1);
      char* sbw = (t < 2 ? slab01 + (size_t)t * 65536
                         : preb + (size_t)(t - 2) * 262144) + (size_t)bg * (t < 2 ? 16384 : 65536);
      uint32_t pk = (uint32_t)f2bf(h0) | ((uint32_t)f2bf(h1) << 16);
      __hip_atomic_store((uint32_t*)(sbw + erow * 1024 + (cg * 32 + wv * 8 + es * 2) * 2),
                         pk, __ATOMIC_RELAXED, __HIP_MEMORY_SCOPE_AGENT);
      if (t == 255) {
        size_t idx = (size_t)(bg * 16 + erow) * 512 + cg * 32 + wv * 8 + es * 2;
        hfin[idx] = h0; hfin[idx + 1] = h1;
        cfin[idx] = c0; cfin[idx + 1] = c1;
      }
    }
    __syncthreads();  // drains vmcnt(0): payload at LLC before flag
    if (tid == 0)
      __hip_atomic_store(&flags[bg * 16 + cg], t + 1, __ATOMIC_RELAXED, __HIP_MEMORY_SCOPE_AGENT);

    // register prefetch of pre strip for t+1 (hidden under next poll window)
    if (t < 255) {
      int tn = t + 1;
      wait_mtile(tn >> 1);
#pragma unroll
      for (int nt = 0; nt < 2; ++nt)
#pragma unroll
        for (int r = 0; r < 4; ++r)
          pr[nt * 4 + r] = pre[(size_t)(tn * 64 + bg * 16 + q * 4 + r) * 2048 + N0 + wv * 32 + nt * 16 + l16];
    }
  }
}

// ---------- 6. final: out = h @ W_lin + b_lin; copy h, c ----------
__global__ __launch_bounds__(256) void k_final(const float* __restrict__ h, const float* __restrict__ c,
                                               const float* __restrict__ wl, const float* __restrict__ bl,
                                               float* __restrict__ out) {
  __shared__ float red[256];
  int b = blockIdx.x, t = threadIdx.x;
  const float* hb = h + (size_t)b * 512;
  if (t < 128) {
    ((float4*)(out + 320 + (size_t)b * 512))[t] = ((const float4*)hb)[t];
    ((float4*)(out + 320 + 32768 + (size_t)b * 512))[t] = ((const float4*)(c + (size_t)b * 512))[t];
  }
  float h0 = hb[t], h1 = hb[t + 256];
  for (int o = 0; o < 5; ++o) {
    red[t] = h0 * wl[t * 5 + o] + h1 * wl[(t + 256) * 5 + o];
    __syncthreads();
    for (int s = 128; s > 0; s >>= 1) {
      if (t < s) red[t] += red[t + s];
      __syncthreads();
    }
    if (t == 0) out[b * 5 + o] = red[0] + bl[o];
    __syncthreads();
  }
}

// ---------- launch ----------
extern "C" void kernel_launch(void* const* d_in, const int* in_sizes, int n_in,
                              void* d_out, int out_size, void* d_ws, size_t ws_size,
                              hipStream_t stream) {
  const int*   x   = (const int*)d_in[0];
  const float* emb = (const float*)d_in[1];
  const float* wfx = (const float*)d_in[2];
  const float* wfh = (const float*)d_in[3];
  const float* bf_ = (const float*)d_in[4];
  const float* wix = (const float*)d_in[5];
  const float* wih = (const float*)d_in[6];
  const float* bi_ = (const float*)d_in[7];
  const float* wgx = (const float*)d_in[8];
  const float* wgh = (const float*)d_in[9];
  const float* bg_ = (const float*)d_in[10];
  const float* wox = (const float*)d_in[11];
  const float* woh = (const float*)d_in[12];
  const float* bo_ = (const float*)d_in[13];
  const float* wl  = (const float*)d_in[14];
  const float* bl  = (const float*)d_in[15];
  float* out = (float*)d_out;
  char* ws = (char*)d_ws;

  uint16_t* embbf = (uint16_t*)(ws + OFF_EMB);
  uint16_t* wxt   = (uint16_t*)(ws + OFF_WXT);
  uint16_t* wht   = (uint16_t*)(ws + OFF_WHT);
  float*    bias  = (float*)(ws + OFF_BIAS);
  uint16_t* pre   = (uint16_t*)(ws + OFF_PRE);
  float*    hfin  = (float*)(ws + OFF_HF);
  float*    cfin  = (float*)(ws + OFF_CF);
  int*      cnt   = (int*)(ws + OFF_CNT);

  hipMemsetAsync(ws + OFF_CNT, 0, 4096, stream);  // cnt[128] + flags[64]

  hipLaunchKernelGGL(k_emb_cvt, dim3(6250), dim3(256), 0, stream, emb, embbf);
  hipLaunchKernelGGL(k_wt, dim3(64, 32), dim3(256), 0, stream, wfx, wix, wgx, wox, 4096, wxt);
  hipLaunchKernelGGL(k_wt, dim3(8, 32), dim3(256), 0, stream, wfh, wih, wgh, woh, 512, wht);
  hipLaunchKernelGGL(k_bias, dim3(8), dim3(256), 0, stream, bf_, bi_, bg_, bo_, bias);
  hipLaunchKernelGGL(k_main, dim3(64 + 2048), dim3(256), 0, stream,
                     embbf, x, wxt, pre, (char*)(ws + OFF_PRE), ws + OFF_SLAB01,
                     wht, bias, cnt, hfin, cfin);
  hipLaunchKernelGGL(k_final, dim3(64), dim3(256), 0, stream, hfin, cfin, wl, bl, out);
}

// Round 6
// 1021.273 us; speedup vs baseline: 1.4047x; 1.4047x over previous
//
#include <hip/hip_runtime.h>
#include <stdint.h>

#define DEVI __device__ __forceinline__
typedef unsigned long long ull;

typedef __bf16 bf16x8 __attribute__((ext_vector_type(8)));
typedef float floatx4 __attribute__((ext_vector_type(4)));
typedef unsigned int u32x4 __attribute__((ext_vector_type(4)));

// ---------- helpers ----------
DEVI uint16_t f2bf(float f) {
  union { float f; uint32_t u; } c; c.f = f;
  uint32_t u = c.u;
  return (uint16_t)((u + 0x7fffu + ((u >> 16) & 1u)) >> 16);  // RNE
}
DEVI float bf2f(uint16_t h) {
  union { uint32_t u; float f; } c; c.u = ((uint32_t)h) << 16;
  return c.f;
}
DEVI void load_lds_16(const void* g, void* l) {
  __builtin_amdgcn_global_load_lds(
      (const __attribute__((address_space(1))) void*)g,
      (__attribute__((address_space(3))) void*)l, 16, 0, 0);
}
DEVI float sigm(float x) { return 1.f / (1.f + __expf(-x)); }
DEVI float tanh_s(float x) {
  float xc = fminf(fmaxf(x, -15.f), 15.f);
  float e = __expf(2.f * xc);
  return (e - 1.f) / (e + 1.f);
}

// ---------- workspace layout (bytes) ----------
// pre [256][64][2048] bf16; tagged-h slab for step t>=2 aliases pre[t-2]
// (first 32KB of each bg's 64KB row-group; serial k_gemm->k_rec dispatch
// boundary flushes L2, and slab accesses are cache-bypassing).
// Slab(t,bg): [16 rows][2048B], pair p at p*8 = [bf16x2 payload | tag=t+1].
static constexpr size_t OFF_EMB    = 0;                        // [50000][256] bf16
static constexpr size_t OFF_WXT    = 25600000;                 // [2048][4096] bf16
static constexpr size_t OFF_WHT    = OFF_WXT + 16777216;       // [2048][512] bf16
static constexpr size_t OFF_BIAS   = OFF_WHT + 2097152;        // [2048] f32
static constexpr size_t OFF_PRE    = OFF_BIAS + 8192;          // [256][64][2048] bf16
static constexpr size_t OFF_HF     = OFF_PRE + 67108864 + 4096;
static constexpr size_t OFF_CF     = OFF_HF + 131072;
static constexpr size_t OFF_CNT    = OFF_CF + 131072;          // (unused this round)
static constexpr size_t OFF_SLAB01 = OFF_CNT + 4096;           // 2 x 262144 slabs t=0,1 (poison!=tag)

// ---------- 1. embedding -> bf16, row 0 zeroed ----------
__global__ __launch_bounds__(256) void k_emb_cvt(const float* __restrict__ emb,
                                                 uint16_t* __restrict__ dst) {
  size_t tid = (size_t)blockIdx.x * 256 + threadIdx.x;
  size_t e = tid * 8;
  int v = (int)(e >> 8);
  const float4* s = (const float4*)(emb + e);
  float4 f0 = s[0], f1 = s[1];
  if (v == 0) { f0 = make_float4(0.f, 0.f, 0.f, 0.f); f1 = f0; }
  uint32_t w0 = f2bf(f0.x) | ((uint32_t)f2bf(f0.y) << 16);
  uint32_t w1 = f2bf(f0.z) | ((uint32_t)f2bf(f0.w) << 16);
  uint32_t w2 = f2bf(f1.x) | ((uint32_t)f2bf(f1.y) << 16);
  uint32_t w3 = f2bf(f1.z) | ((uint32_t)f2bf(f1.w) << 16);
  *(uint4*)(dst + e) = make_uint4(w0, w1, w2, w3);
}

// ---------- 2. weight transpose+convert: W_g[K][512] -> dst[n=h*4+g][K] bf16 ----------
__global__ __launch_bounds__(256) void k_wt(const float* __restrict__ w0, const float* __restrict__ w1,
                                            const float* __restrict__ w2, const float* __restrict__ w3,
                                            int K, uint16_t* __restrict__ dst) {
  __shared__ float tile[64 * 64];
  int k0 = blockIdx.x * 64;
  int n0 = blockIdx.y * 64;
  int h0 = blockIdx.y * 16;
  int g = threadIdx.x >> 6, di = threadIdx.x & 63;
  const float* w = (g == 0) ? w0 : (g == 1) ? w1 : (g == 2) ? w2 : w3;
  const float4* src = (const float4*)(w + (size_t)(k0 + di) * 512 + h0);
  float4 a = src[0], b = src[1], c = src[2], d = src[3];
  float vals[16] = {a.x, a.y, a.z, a.w, b.x, b.y, b.z, b.w,
                    c.x, c.y, c.z, c.w, d.x, d.y, d.z, d.w};
#pragma unroll
  for (int dh = 0; dh < 16; ++dh) tile[(dh * 4 + g) * 64 + di] = vals[dh];
  __syncthreads();
  int nl = threadIdx.x >> 2, ch = threadIdx.x & 3;
  uint32_t wb[8];
#pragma unroll
  for (int j = 0; j < 8; ++j) {
    float lo = tile[nl * 64 + ch * 16 + j * 2];
    float hi = tile[nl * 64 + ch * 16 + j * 2 + 1];
    wb[j] = f2bf(lo) | ((uint32_t)f2bf(hi) << 16);
  }
  uint4* dp = (uint4*)(dst + (size_t)(n0 + nl) * K + k0 + ch * 16);
  dp[0] = make_uint4(wb[0], wb[1], wb[2], wb[3]);
  dp[1] = make_uint4(wb[4], wb[5], wb[6], wb[7]);
}

// ---------- 3. bias pack ----------
__global__ __launch_bounds__(256) void k_bias(const float* __restrict__ b0, const float* __restrict__ b1,
                                              const float* __restrict__ b2, const float* __restrict__ b3,
                                              float* __restrict__ dst) {
  int n = blockIdx.x * 256 + threadIdx.x;
  int h = n >> 2, g = n & 3;
  const float* b = (g == 0) ? b0 : (g == 1) ? b1 : (g == 2) ? b2 : b3;
  dst[n] = b[h];
}

// ---------- 4. gather-GEMM (unchanged, known-good) ----------
__global__ __launch_bounds__(256) void k_gemm(const uint16_t* __restrict__ embbf,
                                              const int* __restrict__ x,
                                              const uint16_t* __restrict__ wxt,
                                              uint16_t* __restrict__ pre) {
  __shared__ uint16_t As[128 * 64];
  __shared__ uint16_t Bs[128 * 64];
  const int tid = threadIdx.x;
  const int wv = tid >> 6, ln = tid & 63;
  const int wm = wv >> 1, wn = wv & 1;
  const int M0 = blockIdx.x * 128, N0 = blockIdx.y * 128;
  const int srow = ln >> 3, schunk = ln & 7;

  const int* xrow[4];
  const uint16_t* bbase[4];
  uint16_t* ldsA[4];
  uint16_t* ldsB[4];
#pragma unroll
  for (int j = 0; j < 4; ++j) {
    int r = j * 32 + wv * 8 + srow;
    int m = M0 + r;
    int t = m >> 6, b = m & 63;
    xrow[j] = x + b * 4096 + t;
    bbase[j] = wxt + (size_t)(N0 + r) * 4096 + schunk * 8;
    ldsA[j] = As + (j * 32 + wv * 8) * 64;
    ldsB[j] = Bs + (j * 32 + wv * 8) * 64;
  }

  const int q = ln >> 4, l16 = ln & 15;
  int aoff[4], boff[4];
#pragma unroll
  for (int mt = 0; mt < 4; ++mt) aoff[mt] = (wm * 64 + mt * 16 + l16) * 64 + q * 8;
#pragma unroll
  for (int nt = 0; nt < 4; ++nt) boff[nt] = (wn * 64 + nt * 16 + l16) * 64 + q * 8;

  floatx4 acc[4][4] = {};

  for (int p = 0; p < 16; ++p) {
    const uint16_t* abase[4];
#pragma unroll
    for (int j = 0; j < 4; ++j) {
      int idx = xrow[j][p << 8];
      abase[j] = embbf + (size_t)idx * 256 + schunk * 8;
    }
#pragma unroll 1
    for (int ki = 0; ki < 4; ++ki) {
      __syncthreads();
#pragma unroll
      for (int j = 0; j < 4; ++j) load_lds_16(abase[j] + ki * 64, ldsA[j]);
#pragma unroll
      for (int j = 0; j < 4; ++j) load_lds_16(bbase[j] + p * 256 + ki * 64, ldsB[j]);
      __syncthreads();
#pragma unroll
      for (int kk = 0; kk < 2; ++kk) {
        bf16x8 a[4];
#pragma unroll
        for (int mt = 0; mt < 4; ++mt) a[mt] = *(const bf16x8*)(As + aoff[mt] + kk * 32);
#pragma unroll
        for (int nt = 0; nt < 4; ++nt) {
          bf16x8 bv = *(const bf16x8*)(Bs + boff[nt] + kk * 32);
#pragma unroll
          for (int mt = 0; mt < 4; ++mt)
            acc[mt][nt] = __builtin_amdgcn_mfma_f32_16x16x32_bf16(a[mt], bv, acc[mt][nt], 0, 0, 0);
        }
      }
    }
  }

#pragma unroll
  for (int mt = 0; mt < 4; ++mt) {
    int mg = M0 + wm * 64 + mt * 16 + q * 4;
#pragma unroll
    for (int nt = 0; nt < 4; ++nt) {
      int ng = N0 + wn * 64 + nt * 16 + l16;
#pragma unroll
      for (int r = 0; r < 4; ++r)
        pre[(size_t)(mg + r) * 2048 + ng] = f2bf(acc[mt][nt][r]);
    }
  }
}

// ---------- 5. persistent recurrence: tagged single-RT exchange, wide bypass loads ----------
// 64 WGs = 4 bg x 16 cg. Wave wv owns gate-cols [N0+wv*32,+32) end-to-end.
// h_t: 8B (bf16x2|tag) units; producer 8B agent-atomic stores; consumer polls
// with global_load_dwordx4 sc0 sc1 (coalesced, cache-bypassing, tag-verified).
__global__ __launch_bounds__(256) void k_rec(const uint16_t* pre,  // aliased by slabs
                                             char* preb,
                                             char* scratch,
                                             const uint16_t* __restrict__ wht,
                                             const float* __restrict__ biasp,
                                             float* __restrict__ hfin,
                                             float* __restrict__ cfin) {
  __shared__ uint16_t Ahs[2][16 * 528];     // stride 528: conflict-free b64 writes + b128 reads
  __shared__ float gates[16 * 132];

  const int tid = threadIdx.x;
  const int wv = tid >> 6, ln = tid & 63;
  const int q = ln >> 4, l16 = ln & 15;
  const int bg = blockIdx.x >> 4, cg = blockIdx.x & 15;
  const int N0 = cg * 128;

  // B fragments resident: wave wv owns n-cols N0 + wv*32 .. +32
  bf16x8 Bfrag[16][2];
#pragma unroll
  for (int kc = 0; kc < 16; ++kc)
#pragma unroll
    for (int nt = 0; nt < 2; ++nt) {
      int n = N0 + wv * 32 + nt * 16 + l16;
      Bfrag[kc][nt] = *(const bf16x8*)(wht + (size_t)n * 512 + kc * 32 + q * 8);
    }
  float breg[2];
#pragma unroll
  for (int nt = 0; nt < 2; ++nt) breg[nt] = biasp[N0 + wv * 32 + nt * 16 + l16];

  const int prow = tid >> 4;                // poll row 0..15
  const int pseg = tid & 15;                // 16B segment within 256B chunk
  const int erow = ln >> 2;
  const int es = ln & 3;
  float creg[2] = {0.f, 0.f};

  // zero Ahs[0] (t=0 state h=0)
  for (int i = tid; i < 4224; i += 256) ((uint32_t*)Ahs[0])[i] = 0;

  // register prefetch of pre strip for t=0
  uint16_t pr[8];
#pragma unroll
  for (int nt = 0; nt < 2; ++nt)
#pragma unroll
    for (int r = 0; r < 4; ++r)
      pr[nt * 4 + r] = pre[(size_t)(bg * 16 + q * 4 + r) * 2048 + N0 + wv * 32 + nt * 16 + l16];

  for (int t = 0; t < 256; ++t) {
    if (t > 0) {
      const char* sb = ((t - 1) < 2 ? scratch + (size_t)(t - 1) * 262144
                                    : preb + (size_t)(t - 3) * 262144) + (size_t)bg * 65536;
      const char* base = sb + prow * 2048 + pseg * 16;
      const uint32_t want = (uint32_t)t;
      u32x4 u0, u1, u2, u3, u4, u5, u6, u7;
      for (;;) {
        asm volatile(
            "global_load_dwordx4 %0, %8, off sc0 sc1\n\t"
            "global_load_dwordx4 %1, %8, off offset:256 sc0 sc1\n\t"
            "global_load_dwordx4 %2, %8, off offset:512 sc0 sc1\n\t"
            "global_load_dwordx4 %3, %8, off offset:768 sc0 sc1\n\t"
            "global_load_dwordx4 %4, %8, off offset:1024 sc0 sc1\n\t"
            "global_load_dwordx4 %5, %8, off offset:1280 sc0 sc1\n\t"
            "global_load_dwordx4 %6, %8, off offset:1536 sc0 sc1\n\t"
            "global_load_dwordx4 %7, %8, off offset:1792 sc0 sc1\n\t"
            "s_waitcnt vmcnt(0)"
            : "=v"(u0), "=v"(u1), "=v"(u2), "=v"(u3),
              "=v"(u4), "=v"(u5), "=v"(u6), "=v"(u7)
            : "v"(base)
            : "memory");
        bool ok = (u0.y == want) && (u0.w == want) && (u1.y == want) && (u1.w == want) &&
                  (u2.y == want) && (u2.w == want) && (u3.y == want) && (u3.w == want) &&
                  (u4.y == want) && (u4.w == want) && (u5.y == want) && (u5.w == want) &&
                  (u6.y == want) && (u6.w == want) && (u7.y == want) && (u7.w == want);
        if (ok) break;
        __builtin_amdgcn_s_sleep(1);
      }
      // stage payloads: col = 4*pseg + 64*j, contiguous 4 cols per u32x4
      uint16_t* dr = Ahs[t & 1] + prow * 528 + pseg * 4;
      *(ull*)(dr +   0) = (ull)u0.x | ((ull)u0.z << 32);
      *(ull*)(dr +  64) = (ull)u1.x | ((ull)u1.z << 32);
      *(ull*)(dr + 128) = (ull)u2.x | ((ull)u2.z << 32);
      *(ull*)(dr + 192) = (ull)u3.x | ((ull)u3.z << 32);
      *(ull*)(dr + 256) = (ull)u4.x | ((ull)u4.z << 32);
      *(ull*)(dr + 320) = (ull)u5.x | ((ull)u5.z << 32);
      *(ull*)(dr + 384) = (ull)u6.x | ((ull)u6.z << 32);
      *(ull*)(dr + 448) = (ull)u7.x | ((ull)u7.z << 32);
    }
    __syncthreads();  // the one barrier per step

    // MFMA [16 x 512] x [512 x 32] per wave, 2 chains of 8
    const uint16_t* Ab = Ahs[t & 1];
    floatx4 a0[2] = {}, a1[2] = {};
#pragma unroll
    for (int kc = 0; kc < 8; ++kc) {
      bf16x8 a = *(const bf16x8*)(Ab + l16 * 528 + kc * 32 + q * 8);
#pragma unroll
      for (int nt = 0; nt < 2; ++nt)
        a0[nt] = __builtin_amdgcn_mfma_f32_16x16x32_bf16(a, Bfrag[kc][nt], a0[nt], 0, 0, 0);
    }
#pragma unroll
    for (int kc = 8; kc < 16; ++kc) {
      bf16x8 a = *(const bf16x8*)(Ab + l16 * 528 + kc * 32 + q * 8);
#pragma unroll
      for (int nt = 0; nt < 2; ++nt)
        a1[nt] = __builtin_amdgcn_mfma_f32_16x16x32_bf16(a, Bfrag[kc][nt], a1[nt], 0, 0, 0);
    }

    // gates = acc + bias + pre (registers, wave-local columns)
#pragma unroll
    for (int nt = 0; nt < 2; ++nt) {
      int n_l = wv * 32 + nt * 16 + l16;
      floatx4 s = a0[nt] + a1[nt];
#pragma unroll
      for (int r = 0; r < 4; ++r) {
        int row = q * 4 + r;
        gates[row * 132 + n_l] = s[r] + breg[nt] + bf2f(pr[nt * 4 + r]);
      }
    }
    // wave-local LDS exchange: compiler inserts lgkmcnt wait, no barrier

    // epilogue: 2 h-units per lane; tagged 8B agent store
    {
      float4 v0 = *(const float4*)(gates + erow * 132 + wv * 32 + es * 8);
      float4 v1 = *(const float4*)(gates + erow * 132 + wv * 32 + es * 8 + 4);
      float f0 = sigm(v0.x), i0 = sigm(v0.y), g0 = tanh_s(v0.z), o0 = sigm(v0.w);
      float f1 = sigm(v1.x), i1 = sigm(v1.y), g1 = tanh_s(v1.z), o1 = sigm(v1.w);
      float c0 = f0 * creg[0] + i0 * g0; creg[0] = c0;
      float c1 = f1 * creg[1] + i1 * g1; creg[1] = c1;
      float h0 = o0 * tanh_s(c0), h1 = o1 * tanh_s(c1);
      char* sbw = (t < 2 ? scratch + (size_t)t * 262144
                         : preb + (size_t)(t - 2) * 262144) + (size_t)bg * 65536;
      int pair = cg * 16 + wv * 4 + es;
      ull pk = (ull)((uint32_t)f2bf(h0) | ((uint32_t)f2bf(h1) << 16)) |
               ((ull)(uint32_t)(t + 1) << 32);
      __hip_atomic_store((ull*)(sbw + erow * 2048 + pair * 8),
                         pk, __ATOMIC_RELAXED, __HIP_MEMORY_SCOPE_AGENT);
      if (t == 255) {
        size_t idx = (size_t)(bg * 16 + erow) * 512 + cg * 32 + wv * 8 + es * 2;
        hfin[idx] = h0; hfin[idx + 1] = h1;
        cfin[idx] = c0; cfin[idx + 1] = c1;
      }
    }

    // register prefetch of pre strip for t+1 (hidden under next poll window)
    if (t < 255) {
      int tn = t + 1;
#pragma unroll
      for (int nt = 0; nt < 2; ++nt)
#pragma unroll
        for (int r = 0; r < 4; ++r)
          pr[nt * 4 + r] = pre[(size_t)(tn * 64 + bg * 16 + q * 4 + r) * 2048 + N0 + wv * 32 + nt * 16 + l16];
    }
  }
}

// ---------- 6. final: out = h @ W_lin + b_lin; copy h, c ----------
__global__ __launch_bounds__(256) void k_final(const float* __restrict__ h, const float* __restrict__ c,
                                               const float* __restrict__ wl, const float* __restrict__ bl,
                                               float* __restrict__ out) {
  __shared__ float red[256];
  int b = blockIdx.x, t = threadIdx.x;
  const float* hb = h + (size_t)b * 512;
  if (t < 128) {
    ((float4*)(out + 320 + (size_t)b * 512))[t] = ((const float4*)hb)[t];
    ((float4*)(out + 320 + 32768 + (size_t)b * 512))[t] = ((const float4*)(c + (size_t)b * 512))[t];
  }
  float h0 = hb[t], h1 = hb[t + 256];
  for (int o = 0; o < 5; ++o) {
    red[t] = h0 * wl[t * 5 + o] + h1 * wl[(t + 256) * 5 + o];
    __syncthreads();
    for (int s = 128; s > 0; s >>= 1) {
      if (t < s) red[t] += red[t + s];
      __syncthreads();
    }
    if (t == 0) out[b * 5 + o] = red[0] + bl[o];
    __syncthreads();
  }
}

// ---------- launch ----------
extern "C" void kernel_launch(void* const* d_in, const int* in_sizes, int n_in,
                              void* d_out, int out_size, void* d_ws, size_t ws_size,
                              hipStream_t stream) {
  const int*   x   = (const int*)d_in[0];
  const float* emb = (const float*)d_in[1];
  const float* wfx = (const float*)d_in[2];
  const float* wfh = (const float*)d_in[3];
  const float* bf_ = (const float*)d_in[4];
  const float* wix = (const float*)d_in[5];
  const float* wih = (const float*)d_in[6];
  const float* bi_ = (const float*)d_in[7];
  const float* wgx = (const float*)d_in[8];
  const float* wgh = (const float*)d_in[9];
  const float* bg_ = (const float*)d_in[10];
  const float* wox = (const float*)d_in[11];
  const float* woh = (const float*)d_in[12];
  const float* bo_ = (const float*)d_in[13];
  const float* wl  = (const float*)d_in[14];
  const float* bl  = (const float*)d_in[15];
  float* out = (float*)d_out;
  char* ws = (char*)d_ws;

  uint16_t* embbf = (uint16_t*)(ws + OFF_EMB);
  uint16_t* wxt   = (uint16_t*)(ws + OFF_WXT);
  uint16_t* wht   = (uint16_t*)(ws + OFF_WHT);
  float*    bias  = (float*)(ws + OFF_BIAS);
  uint16_t* pre   = (uint16_t*)(ws + OFF_PRE);
  float*    hfin  = (float*)(ws + OFF_HF);
  float*    cfin  = (float*)(ws + OFF_CF);

  hipLaunchKernelGGL(k_emb_cvt, dim3(6250), dim3(256), 0, stream, emb, embbf);
  hipLaunchKernelGGL(k_wt, dim3(64, 32), dim3(256), 0, stream, wfx, wix, wgx, wox, 4096, wxt);
  hipLaunchKernelGGL(k_wt, dim3(8, 32), dim3(256), 0, stream, wfh, wih, wgh, woh, 512, wht);
  hipLaunchKernelGGL(k_bias, dim3(8), dim3(256), 0, stream, bf_, bi_, bg_, bo_, bias);
  hipLaunchKernelGGL(k_gemm, dim3(128, 16), dim3(256), 0, stream, embbf, x, wxt, pre);
  hipLaunchKernelGGL(k_rec, dim3(64), dim3(256), 0, stream, pre, (char*)(ws + OFF_PRE),
                     ws + OFF_SLAB01, wht, bias, hfin, cfin);
  hipLaunchKernelGGL(k_final, dim3(64), dim3(256), 0, stream, hfin, cfin, wl, bl, out);
}